// Round 2
// baseline (986.199 us; speedup 1.0000x reference)
//
#include <hip/hip_runtime.h>
#include <stdint.h>

#define SEQ 128
#define BATCH 256
#define INPUT_BITS 256
#define STATE_BITS 256
#define N_IN 1024
#define N_ST 256
#define NB 16
#define RAM_WORDS 2048   // 2^16 bits / 32 bits per word

// Pack an array of "bool encoded as 32-bit nonzero" into a bitmask array.
// One source element per thread; wave-wide ballot -> 2 output words per wave.
__global__ void pack_bits_kernel(const uint32_t* __restrict__ src,
                                 uint32_t* __restrict__ dst) {
    int i = blockIdx.x * blockDim.x + threadIdx.x;
    uint32_t v = src[i];
    uint64_t m = __ballot(v != 0u);
    int lane = threadIdx.x & 63;
    if ((lane & 31) == 0) {
        dst[i >> 5] = (uint32_t)(m >> (lane & 32));
    }
}

__global__ __launch_bounds__(1024)
void ram_automaton_kernel(
    const uint32_t* __restrict__ seq_bits,   // [SEQ][BATCH][INPUT_BITS] bool-as-i32
    const uint32_t* __restrict__ init_state, // [BATCH][STATE_BITS]
    const int*      __restrict__ input_conn, // [N_IN][NB]
    const int*      __restrict__ state_conn, // [N_ST][NB]
    const uint32_t* __restrict__ pim,        // packed input_mem [N_IN][RAM_WORDS] (or null)
    const uint32_t* __restrict__ psm,        // packed state_mem [N_ST][RAM_WORDS] (or null)
    const uint32_t* __restrict__ im_raw,     // raw input_mem [N_IN][65536]
    const uint32_t* __restrict__ sm_raw,     // raw state_mem [N_ST][65536]
    int* __restrict__ outs,                  // [SEQ][BATCH][N_IN] int32 0/1
    int* __restrict__ final_state,           // [BATCH][N_ST] int32 0/1
    int packed)
{
    __shared__ uint32_t c0[16];  // [input bits (8 words) | state (8 words)]
    __shared__ uint32_t c1[40];  // [io bits (32 words)   | state (8 words)]

    const int b = blockIdx.x;
    const int tid = threadIdx.x;
    const int lane = tid & 63;

    // Load connection tables into registers (reused for all 128 steps).
    int ic[NB];
#pragma unroll
    for (int k = 0; k < NB; k++) ic[k] = input_conn[tid * NB + k];
    int sc[NB];
    if (tid < N_ST) {
#pragma unroll
        for (int k = 0; k < NB; k++) sc[k] = state_conn[tid * NB + k];
    }

    // Initial state -> c0[8..16) and c1[32..40)
    if (tid < STATE_BITS) {
        uint32_t v = init_state[(size_t)b * STATE_BITS + tid];
        uint64_t m = __ballot(v != 0u);
        if ((lane & 31) == 0) {
            uint32_t w = (uint32_t)(m >> (lane & 32));
            c0[8 + (tid >> 5)] = w;
            c1[32 + (tid >> 5)] = w;
        }
    }
    __syncthreads();

    for (int t = 0; t < SEQ; t++) {
        // Phase A: this step's input bits -> c0[0..8)
        if (tid < INPUT_BITS) {
            uint32_t v = seq_bits[((size_t)t * BATCH + b) * INPUT_BITS + tid];
            uint64_t m = __ballot(v != 0u);
            if ((lane & 31) == 0) c0[tid >> 5] = (uint32_t)(m >> (lane & 32));
        }
        __syncthreads();

        // Phase B: input layer, neuron n = tid
        {
            int addr = 0;
#pragma unroll
            for (int k = 0; k < NB; k++) {
                int c = ic[k];
                uint32_t w = c0[c >> 5];
                addr |= (int)((w >> (c & 31)) & 1u) << k;
            }
            uint32_t bit;
            if (packed) {
                uint32_t w = pim[(tid << 11) + (addr >> 5)];
                bit = (w >> (addr & 31)) & 1u;
            } else {
                bit = (im_raw[((size_t)tid << 16) + (size_t)addr] != 0u) ? 1u : 0u;
            }
            outs[((size_t)t * BATCH + b) * N_IN + tid] = (int)bit;
            uint64_t m = __ballot(bit != 0u);
            if (lane == 0) {
                c1[(tid >> 5)]     = (uint32_t)m;
                c1[(tid >> 5) + 1] = (uint32_t)(m >> 32);
            }
        }
        __syncthreads();

        // Phase C1: state layer compute (reads c1, no writes yet)
        uint32_t nsbit = 0;
        if (tid < N_ST) {
            int addr = 0;
#pragma unroll
            for (int k = 0; k < NB; k++) {
                int c = sc[k];
                uint32_t w = c1[c >> 5];
                addr |= (int)((w >> (c & 31)) & 1u) << k;
            }
            if (packed) {
                uint32_t w = psm[(tid << 11) + (addr >> 5)];
                nsbit = (w >> (addr & 31)) & 1u;
            } else {
                nsbit = (sm_raw[((size_t)tid << 16) + (size_t)addr] != 0u) ? 1u : 0u;
            }
        }
        __syncthreads();

        // Phase C2: commit new state into c0[8..16) and c1[32..40)
        if (tid < N_ST) {
            uint64_t m = __ballot(nsbit != 0u);
            if ((lane & 31) == 0) {
                uint32_t w = (uint32_t)(m >> (lane & 32));
                c0[8 + (tid >> 5)]  = w;
                c1[32 + (tid >> 5)] = w;
            }
        }
        __syncthreads();
    }

    if (tid < N_ST) {
        uint32_t w = c0[8 + (tid >> 5)];
        final_state[(size_t)b * N_ST + tid] = (int)((w >> (tid & 31)) & 1u);
    }
}

extern "C" void kernel_launch(void* const* d_in, const int* in_sizes, int n_in,
                              void* d_out, int out_size, void* d_ws, size_t ws_size,
                              hipStream_t stream) {
    const uint32_t* seq        = (const uint32_t*)d_in[0]; // input_seq_bits
    const uint32_t* init_state = (const uint32_t*)d_in[1]; // init_state
    const int*      input_conn = (const int*)d_in[2];      // input_conn
    const uint32_t* input_mem  = (const uint32_t*)d_in[3]; // input_mem
    const int*      state_conn = (const int*)d_in[4];      // state_conn
    const uint32_t* state_mem  = (const uint32_t*)d_in[5]; // state_mem

    int* outs = (int*)d_out;                               // [SEQ][BATCH][N_IN]
    int* fin  = outs + (size_t)SEQ * BATCH * N_IN;         // [BATCH][N_ST]

    const size_t pim_words = (size_t)N_IN * RAM_WORDS;  // 2,097,152 (8 MB)
    const size_t psm_words = (size_t)N_ST * RAM_WORDS;  //   524,288 (2 MB)
    const size_t need = (pim_words + psm_words) * sizeof(uint32_t);

    uint32_t* pim = nullptr;
    uint32_t* psm = nullptr;
    int packed = 0;
    if (ws_size >= need) {
        packed = 1;
        pim = (uint32_t*)d_ws;
        psm = pim + pim_words;
        hipLaunchKernelGGL(pack_bits_kernel,
                           dim3((N_IN * 65536) / 256), dim3(256), 0, stream,
                           input_mem, pim);
        hipLaunchKernelGGL(pack_bits_kernel,
                           dim3((N_ST * 65536) / 256), dim3(256), 0, stream,
                           state_mem, psm);
    }

    hipLaunchKernelGGL(ram_automaton_kernel, dim3(BATCH), dim3(1024), 0, stream,
                       seq, init_state, input_conn, state_conn,
                       pim, psm, input_mem, state_mem, outs, fin, packed);
}

// Round 4
// 946.119 us; speedup vs baseline: 1.0424x; 1.0424x over previous
//
#include <hip/hip_runtime.h>
#include <stdint.h>

#define SEQ 128
#define BATCH 256
#define INPUT_BITS 256
#define STATE_BITS 256
#define N_IN 1024
#define N_ST 256
#define NB 16
#define RAM_WORDS 2048   // 2^16 bits / 32 bits per word

typedef uint32_t u32x4 __attribute__((ext_vector_type(4)));

// Pack "bool as 32-bit word" -> bitmask. Each thread builds ONE output word
// from 32 consecutive source words (8 x vec4 nt loads).
__global__ __launch_bounds__(256)
void pack_bits_kernel(const u32x4* __restrict__ src, uint32_t* __restrict__ dst) {
    int i = blockIdx.x * blockDim.x + threadIdx.x;   // output word index
    const u32x4* p = src + (size_t)i * 8;
    uint32_t w = 0;
#pragma unroll
    for (int j = 0; j < 8; j++) {
        u32x4 v = __builtin_nontemporal_load(p + j);
        w |= (v.x != 0u ? 1u : 0u) << (4 * j + 0);
        w |= (v.y != 0u ? 1u : 0u) << (4 * j + 1);
        w |= (v.z != 0u ? 1u : 0u) << (4 * j + 2);
        w |= (v.w != 0u ? 1u : 0u) << (4 * j + 3);
    }
    dst[i] = w;
}

__global__ __launch_bounds__(1024)
void ram_automaton_kernel(
    const uint32_t* __restrict__ seq_bits,   // [SEQ][BATCH][INPUT_BITS] bool-as-i32
    const uint32_t* __restrict__ init_state, // [BATCH][STATE_BITS]
    const int*      __restrict__ input_conn, // [N_IN][NB]
    const int*      __restrict__ state_conn, // [N_ST][NB]
    const uint32_t* __restrict__ pim,        // packed input_mem [N_IN][RAM_WORDS] (or null)
    const uint32_t* __restrict__ psm,        // packed state_mem [N_ST][RAM_WORDS] (or null)
    const uint32_t* __restrict__ im_raw,     // raw input_mem [N_IN][65536]
    const uint32_t* __restrict__ sm_raw,     // raw state_mem [N_ST][65536]
    int* __restrict__ outs,                  // [SEQ][BATCH][N_IN] int32 0/1
    int* __restrict__ final_state,           // [BATCH][N_ST] int32 0/1
    int packed)
{
    __shared__ uint32_t c0[16];  // [input bits (8 words) | state (8 words)]
    __shared__ uint32_t c1[40];  // [io bits (32 words)   | state (8 words)]

    const int b = blockIdx.x;
    const int tid = threadIdx.x;
    const int lane = tid & 63;

    // Connection tables in registers (reused for all 128 steps).
    int ic[NB];
#pragma unroll
    for (int k = 0; k < NB; k++) ic[k] = input_conn[tid * NB + k];
    int sc[NB];
    if (tid < N_ST) {
#pragma unroll
        for (int k = 0; k < NB; k++) sc[k] = state_conn[tid * NB + k];
    }

    // Recurrent state bit carried in a register (tid < 256 owns state bit tid).
    uint32_t nsbit = 0;
    if (tid < N_ST) nsbit = (init_state[(size_t)b * STATE_BITS + tid] != 0u) ? 1u : 0u;

    // Prefetched input bit for step t (tid < 256 owns input bit tid).
    uint32_t inbit = 0;
    if (tid < INPUT_BITS) inbit = seq_bits[((size_t)0 * BATCH + b) * INPUT_BITS + tid];

    for (int t = 0; t < SEQ; t++) {
        // Phase A: commit input bits for step t and state (from prev step / init)
        if (tid < INPUT_BITS) {
            uint64_t mi = __ballot(inbit != 0u);
            uint64_t ms = __ballot(nsbit != 0u);
            if ((lane & 31) == 0) {
                c0[tid >> 5] = (uint32_t)(mi >> (lane & 32));
                uint32_t ws = (uint32_t)(ms >> (lane & 32));
                c0[8 + (tid >> 5)]  = ws;
                c1[32 + (tid >> 5)] = ws;
            }
        }
        __syncthreads();

        // Prefetch next step's input bit (non-temporal: streamed once).
        if (t + 1 < SEQ && tid < INPUT_BITS) {
            inbit = __builtin_nontemporal_load(
                seq_bits + ((size_t)(t + 1) * BATCH + b) * INPUT_BITS + tid);
        }

        // Phase B: input layer, neuron n = tid
        {
            int addr = 0;
#pragma unroll
            for (int k = 0; k < NB; k++) {
                int c = ic[k];
                uint32_t w = c0[c >> 5];
                addr |= (int)((w >> (c & 31)) & 1u) << k;
            }
            uint32_t bit;
            if (packed) {
                uint32_t w = pim[(tid << 11) + (addr >> 5)];
                bit = (w >> (addr & 31)) & 1u;
            } else {
                bit = (im_raw[((size_t)tid << 16) + (size_t)addr] != 0u) ? 1u : 0u;
            }
            // Non-temporal store: don't let 134 MB of output evict table lines.
            __builtin_nontemporal_store((int)bit,
                outs + ((size_t)t * BATCH + b) * N_IN + tid);
            uint64_t m = __ballot(bit != 0u);
            if (lane == 0) {
                c1[(tid >> 5)]     = (uint32_t)m;
                c1[(tid >> 5) + 1] = (uint32_t)(m >> 32);
            }
        }
        __syncthreads();

        // Phase C: state layer compute -> register (committed next iteration's A)
        if (tid < N_ST) {
            int addr = 0;
#pragma unroll
            for (int k = 0; k < NB; k++) {
                int c = sc[k];
                uint32_t w = c1[c >> 5];
                addr |= (int)((w >> (c & 31)) & 1u) << k;
            }
            if (packed) {
                uint32_t w = psm[(tid << 11) + (addr >> 5)];
                nsbit = (w >> (addr & 31)) & 1u;
            } else {
                nsbit = (sm_raw[((size_t)tid << 16) + (size_t)addr] != 0u) ? 1u : 0u;
            }
        }
        __syncthreads();
    }

    if (tid < N_ST) {
        final_state[(size_t)b * N_ST + tid] = (int)nsbit;
    }
}

extern "C" void kernel_launch(void* const* d_in, const int* in_sizes, int n_in,
                              void* d_out, int out_size, void* d_ws, size_t ws_size,
                              hipStream_t stream) {
    const uint32_t* seq        = (const uint32_t*)d_in[0]; // input_seq_bits
    const uint32_t* init_state = (const uint32_t*)d_in[1]; // init_state
    const int*      input_conn = (const int*)d_in[2];      // input_conn
    const uint32_t* input_mem  = (const uint32_t*)d_in[3]; // input_mem
    const int*      state_conn = (const int*)d_in[4];      // state_conn
    const uint32_t* state_mem  = (const uint32_t*)d_in[5]; // state_mem

    int* outs = (int*)d_out;                               // [SEQ][BATCH][N_IN]
    int* fin  = outs + (size_t)SEQ * BATCH * N_IN;         // [BATCH][N_ST]

    const size_t pim_words = (size_t)N_IN * RAM_WORDS;  // 2,097,152 (8 MB)
    const size_t psm_words = (size_t)N_ST * RAM_WORDS;  //   524,288 (2 MB)
    const size_t need = (pim_words + psm_words) * sizeof(uint32_t);

    uint32_t* pim = nullptr;
    uint32_t* psm = nullptr;
    int packed = 0;
    if (ws_size >= need) {
        packed = 1;
        pim = (uint32_t*)d_ws;
        psm = pim + pim_words;
        // One output word per thread; 32 source words per thread.
        hipLaunchKernelGGL(pack_bits_kernel,
                           dim3((unsigned)(pim_words / 256)), dim3(256), 0, stream,
                           (const u32x4*)input_mem, pim);
        hipLaunchKernelGGL(pack_bits_kernel,
                           dim3((unsigned)(psm_words / 256)), dim3(256), 0, stream,
                           (const u32x4*)state_mem, psm);
    }

    hipLaunchKernelGGL(ram_automaton_kernel, dim3(BATCH), dim3(1024), 0, stream,
                       seq, init_state, input_conn, state_conn,
                       pim, psm, input_mem, state_mem, outs, fin, packed);
}